// Round 1
// baseline (2343.683 us; speedup 1.0000x reference)
//
#include <hip/hip_runtime.h>
#include <math.h>

#define N_GRID 65160
#define N_MESH 40962
#define N_TOT  106122
#define NE     521280
#define IN_CH  96
#define HID    256
#define OUT_CH 96

// ---------------- concat + transpose: (96,N) channel-major -> (N,96) node-major ----------------
__global__ void k_concat_transpose(const float* __restrict__ xg, const float* __restrict__ xm,
                                   float* __restrict__ h) {
  __shared__ float tile[IN_CH][65];
  int base = blockIdx.x * 64;
  int t = threadIdx.x;
#pragma unroll
  for (int it = 0; it < 24; ++it) {
    int lin = t + it * 256;            // 0..6143 over 96x64
    int c  = lin >> 6;
    int n0 = lin & 63;
    int n = base + n0;
    float v = 0.f;
    if (n < N_TOT) {
      v = (n < N_GRID) ? xg[(size_t)c * N_GRID + n]
                       : xm[(size_t)c * N_MESH + (n - N_GRID)];
    }
    tile[c][n0] = v;
  }
  __syncthreads();
#pragma unroll
  for (int it = 0; it < 24; ++it) {
    int lin = t + it * 256;
    int c  = lin % 96;
    int n0 = lin / 96;
    int n = base + n0;
    if (n < N_TOT) h[(size_t)n * IN_CH + c] = tile[c][n0];
  }
}

// ---------------- degree / dinv ----------------
__global__ void k_fill(float* __restrict__ p, int n, float v) {
  int i = blockIdx.x * 256 + threadIdx.x;
  if (i < n) p[i] = v;
}
__global__ void k_count(const int* __restrict__ dst, float* __restrict__ deg) {
  int e = blockIdx.x * 256 + threadIdx.x;
  if (e < NE) atomicAdd(&deg[dst[e]], 1.0f);
}
__global__ void k_rsqrt(float* __restrict__ p, int n) {
  int i = blockIdx.x * 256 + threadIdx.x;
  if (i < n) p[i] = 1.0f / sqrtf(p[i]);
}

// ---------------- self-loop init: agg[n] = h[n] * dinv[n]^2 (ch4 = channels/4) ----------------
__global__ void k_selfinit(const float* __restrict__ hsrc, const float* __restrict__ dinv,
                           float* __restrict__ agg, int nnodes, int ch4) {
  int i = blockIdx.x * 256 + threadIdx.x;
  int tot = nnodes * ch4;
  if (i >= tot) return;
  int n = i / ch4;
  float w = dinv[n]; w = w * w;
  float4 v = ((const float4*)hsrc)[i];
  ((float4*)agg)[i] = make_float4(v.x * w, v.y * w, v.z * w, v.w * w);
}

// ---------------- edge scatter, 96 channels ----------------
__global__ void k_scatter96(const int* __restrict__ src, const int* __restrict__ dst,
                            const float* __restrict__ dinv, const float* __restrict__ h,
                            float* __restrict__ agg) {
  int i = blockIdx.x * 256 + threadIdx.x;
  if (i >= NE * 24) return;
  int e  = i / 24;
  int c4 = (i % 24) << 2;
  int s = src[e], d = dst[e];
  float w = dinv[s] * dinv[d];
  float4 v = *(const float4*)(h + (size_t)s * 96 + c4);
  float* a = agg + (size_t)d * 96 + c4;
  atomicAdd(a + 0, v.x * w);
  atomicAdd(a + 1, v.y * w);
  atomicAdd(a + 2, v.z * w);
  atomicAdd(a + 3, v.w * w);
}

// ---------------- edge scatter, 256 channels, only dst < N_GRID ----------------
__global__ void k_scatter256(const int* __restrict__ src, const int* __restrict__ dst,
                             const float* __restrict__ dinv, const float* __restrict__ h1,
                             float* __restrict__ agg) {
  int i = blockIdx.x * 256 + threadIdx.x;
  if (i >= NE * 64) return;
  int e  = i >> 6;
  int c4 = (i & 63) << 2;
  int d = dst[e];
  if (d >= N_GRID) return;
  int s = src[e];
  float w = dinv[s] * dinv[d];
  float4 v = *(const float4*)(h1 + (size_t)s * 256 + c4);
  float* a = agg + (size_t)d * 256 + c4;
  atomicAdd(a + 0, v.x * w);
  atomicAdd(a + 1, v.y * w);
  atomicAdd(a + 2, v.z * w);
  atomicAdd(a + 3, v.w * w);
}

// ---------------- fp32 tiled GEMM: C(MxN) = A(MxK) @ W(KxN) + bias, opt. gelu, opt. transposed C ----------------
template<int ACT, bool TRANSC>
__global__ __launch_bounds__(256) void k_gemm(const float* __restrict__ A, const float* __restrict__ W,
                                              const float* __restrict__ bias, float* __restrict__ C,
                                              int M, int K, int N, int ldc) {
  constexpr int BM = 128, BN = 128, BK = 32, TM = 8, TN = 8;
  __shared__ float As[BK][BM + 4];
  __shared__ float Ws[BK][BN + 4];
  int t = threadIdx.x;
  int tx = t & 15, ty = t >> 4;
  int bm = blockIdx.y * BM, bn = blockIdx.x * BN;
  float acc[TM][TN] = {};
  for (int bk = 0; bk < K; bk += BK) {
    // A tile: BM x BK, stored transposed As[k][m]
#pragma unroll
    for (int it = 0; it < 4; ++it) {
      int idx = t + it * 256;          // 0..1023
      int m  = idx >> 3;
      int k4 = (idx & 7) << 2;
      float4 v = make_float4(0.f, 0.f, 0.f, 0.f);
      if (bm + m < M) v = *(const float4*)(A + (size_t)(bm + m) * K + bk + k4);
      As[k4 + 0][m] = v.x;
      As[k4 + 1][m] = v.y;
      As[k4 + 2][m] = v.z;
      As[k4 + 3][m] = v.w;
    }
    // W tile: BK x BN
#pragma unroll
    for (int it = 0; it < 4; ++it) {
      int idx = t + it * 256;
      int k  = idx >> 5;
      int j4 = (idx & 31) << 2;
      float4 v = make_float4(0.f, 0.f, 0.f, 0.f);
      if (bn + j4 < N) v = *(const float4*)(W + (size_t)(bk + k) * N + bn + j4);
      *(float4*)(&Ws[k][j4]) = v;
    }
    __syncthreads();
#pragma unroll
    for (int k = 0; k < BK; ++k) {
      float a[TM], w[TN];
      *(float4*)&a[0] = *(const float4*)(&As[k][ty * TM]);
      *(float4*)&a[4] = *(const float4*)(&As[k][ty * TM + 4]);
      *(float4*)&w[0] = *(const float4*)(&Ws[k][tx * TN]);
      *(float4*)&w[4] = *(const float4*)(&Ws[k][tx * TN + 4]);
#pragma unroll
      for (int im = 0; im < TM; ++im)
#pragma unroll
        for (int jn = 0; jn < TN; ++jn)
          acc[im][jn] += a[im] * w[jn];
    }
    __syncthreads();
  }
#pragma unroll
  for (int im = 0; im < TM; ++im) {
    int gm = bm + ty * TM + im;
    if (gm >= M) continue;
#pragma unroll
    for (int jn = 0; jn < TN; ++jn) {
      int gj = bn + tx * TN + jn;
      if (gj >= N) continue;
      float v = acc[im][jn] + bias[gj];
      if (ACT) v = 0.5f * v * (1.0f + erff(v * 0.70710678118654752f));
      if (TRANSC) C[(size_t)gj * ldc + gm] = v;
      else        C[(size_t)gm * ldc + gj] = v;
    }
  }
}

extern "C" void kernel_launch(void* const* d_in, const int* in_sizes, int n_in,
                              void* d_out, int out_size, void* d_ws, size_t ws_size,
                              hipStream_t stream) {
  const float* xm  = (const float*)d_in[0];   // x: (96, N_MESH)
  const float* xg  = (const float*)d_in[1];   // x_res_grid: (96, N_GRID)
  const int*   ei  = (const int*)d_in[2];     // (2, E): src = ei[0..E), dst = ei[E..2E)
  const float* W1  = (const float*)d_in[3];
  const float* b1  = (const float*)d_in[4];
  const float* W2  = (const float*)d_in[5];
  const float* b2  = (const float*)d_in[6];
  const float* Wl1 = (const float*)d_in[7];
  const float* bl1 = (const float*)d_in[8];
  const float* Wl2 = (const float*)d_in[9];
  const float* bl2 = (const float*)d_in[10];
  float* out = (float*)d_out;

  // workspace layout (floats), with reuse:
  //   region1: 2*N_TOT*96   holds {h, agg1} -> {agg2} -> {t}
  //   region2: N_TOT*256    holds {h1} -> {g}
  //   dinv:    N_TOT
  float* region1 = (float*)d_ws;
  float* region2 = region1 + (size_t)2 * N_TOT * 96;
  float* dinv    = region2 + (size_t)N_TOT * 256;
  float* h    = region1;
  float* agg1 = region1 + (size_t)N_TOT * 96;
  float* h1   = region2;
  float* agg2 = region1;
  float* g    = region2;
  float* tb   = region1;

  const int* esrc = ei;
  const int* edst = ei + NE;
  dim3 b256(256);

  // 1. node features (N_TOT, 96)
  k_concat_transpose<<<dim3((N_TOT + 63) / 64), b256, 0, stream>>>(xg, xm, h);

  // 2. dinv = 1/sqrt(1 + indeg)
  k_fill<<<dim3((N_TOT + 255) / 256), b256, 0, stream>>>(dinv, N_TOT, 1.0f);
  k_count<<<dim3((NE + 255) / 256), b256, 0, stream>>>(edst, dinv);
  k_rsqrt<<<dim3((N_TOT + 255) / 256), b256, 0, stream>>>(dinv, N_TOT);

  // 3. agg1 = S @ h   (96 ch)
  k_selfinit<<<dim3((N_TOT * 24 + 255) / 256), b256, 0, stream>>>(h, dinv, agg1, N_TOT, 24);
  k_scatter96<<<dim3((NE * 24 + 255) / 256), b256, 0, stream>>>(esrc, edst, dinv, h, agg1);

  // 4. h1 = gelu(agg1 @ W1 + b1)   (N_TOT, 256)
  k_gemm<1, false><<<dim3(2, (N_TOT + 127) / 128), b256, 0, stream>>>(agg1, W1, b1, h1, N_TOT, 96, 256, 256);

  // 5. agg2 = S @ h1 restricted to dst < N_GRID   (256 ch)
  k_selfinit<<<dim3((N_GRID * 64 + 255) / 256), b256, 0, stream>>>(h1, dinv, agg2, N_GRID, 64);
  k_scatter256<<<dim3((NE * 64 + 255) / 256), b256, 0, stream>>>(esrc, edst, dinv, h1, agg2);

  // 6. g = agg2 @ W2 + b2   (N_GRID, 256)
  k_gemm<0, false><<<dim3(2, (N_GRID + 127) / 128), b256, 0, stream>>>(agg2, W2, b2, g, N_GRID, 256, 256, 256);

  // 7. t = g @ Wl1 + bl1
  k_gemm<0, false><<<dim3(2, (N_GRID + 127) / 128), b256, 0, stream>>>(g, Wl1, bl1, tb, N_GRID, 256, 256, 256);

  // 8. out^T = (t @ Wl2 + bl2)^T  -> (96, N_GRID)
  k_gemm<0, true><<<dim3(1, (N_GRID + 127) / 128), b256, 0, stream>>>(tb, Wl2, bl2, out, N_GRID, 256, 96, N_GRID);
}

// Round 2
// 718.609 us; speedup vs baseline: 3.2614x; 3.2614x over previous
//
#include <hip/hip_runtime.h>
#include <math.h>

#define N_GRID 65160
#define N_MESH 40962
#define N_TOT  106122
#define NE     521280
#define IN_CH  96
#define HID    256
#define OUT_CH 96

// ---------------- concat + transpose: (96,N) channel-major -> (N,96) node-major ----------------
__global__ void k_concat_transpose(const float* __restrict__ xg, const float* __restrict__ xm,
                                   float* __restrict__ h) {
  __shared__ float tile[IN_CH][65];
  int base = blockIdx.x * 64;
  int t = threadIdx.x;
#pragma unroll
  for (int it = 0; it < 24; ++it) {
    int lin = t + it * 256;            // 0..6143 over 96x64
    int c  = lin >> 6;
    int n0 = lin & 63;
    int n = base + n0;
    float v = 0.f;
    if (n < N_TOT) {
      v = (n < N_GRID) ? xg[(size_t)c * N_GRID + n]
                       : xm[(size_t)c * N_MESH + (n - N_GRID)];
    }
    tile[c][n0] = v;
  }
  __syncthreads();
#pragma unroll
  for (int it = 0; it < 24; ++it) {
    int lin = t + it * 256;
    int c  = lin % 96;
    int n0 = lin / 96;
    int n = base + n0;
    if (n < N_TOT) h[(size_t)n * IN_CH + c] = tile[c][n0];
  }
}

// ---------------- CSR build ----------------
__global__ void k_zeroi(int* __restrict__ p, int n) {
  int i = blockIdx.x * 256 + threadIdx.x;
  if (i < n) p[i] = 0;
}
__global__ void k_seti(int* __restrict__ p, int v) { *p = v; }

__global__ void k_hist(const int* __restrict__ dst, int* __restrict__ deg) {
  int e = blockIdx.x * 256 + threadIdx.x;
  if (e < NE) atomicAdd(&deg[dst[e]], 1);
}

__global__ void k_blocksum(const int* __restrict__ deg, int* __restrict__ bsum, int n) {
  __shared__ int s[256];
  int i = blockIdx.x * 256 + threadIdx.x;
  s[threadIdx.x] = (i < n) ? deg[i] : 0;
  __syncthreads();
  for (int st = 128; st > 0; st >>= 1) {
    if (threadIdx.x < st) s[threadIdx.x] += s[threadIdx.x + st];
    __syncthreads();
  }
  if (threadIdx.x == 0) bsum[blockIdx.x] = s[0];
}

__global__ void k_scanbsum(int* __restrict__ bsum, int nb) {   // single block, 512 thr
  __shared__ int s[512];
  int t = threadIdx.x;
  int v = (t < nb) ? bsum[t] : 0;
  s[t] = v;
  __syncthreads();
  for (int off = 1; off < 512; off <<= 1) {
    int x = (t >= off) ? s[t - off] : 0;
    __syncthreads();
    s[t] += x;
    __syncthreads();
  }
  if (t < nb) bsum[t] = s[t] - v;   // exclusive
}

__global__ void k_offsets(const int* __restrict__ deg, const int* __restrict__ bsum,
                          int* __restrict__ off, int* __restrict__ cur, int n) {
  __shared__ int s[256];
  int i = blockIdx.x * 256 + threadIdx.x;
  int v = (i < n) ? deg[i] : 0;
  s[threadIdx.x] = v;
  __syncthreads();
  for (int o = 1; o < 256; o <<= 1) {
    int x = (threadIdx.x >= o) ? s[threadIdx.x - o] : 0;
    __syncthreads();
    s[threadIdx.x] += x;
    __syncthreads();
  }
  if (i < n) {
    int e = bsum[blockIdx.x] + s[threadIdx.x] - v;
    off[i] = e;
    cur[i] = e;
  }
}

__global__ void k_fillcsr(const int* __restrict__ src, const int* __restrict__ dst,
                          int* __restrict__ cur, int* __restrict__ csrc) {
  int e = blockIdx.x * 256 + threadIdx.x;
  if (e < NE) {
    int p = atomicAdd(&cur[dst[e]], 1);
    csrc[p] = src[e];
  }
}

__global__ void k_dinv(const int* __restrict__ deg, float* __restrict__ dinv, int n) {
  int i = blockIdx.x * 256 + threadIdx.x;
  if (i < n) dinv[i] = rsqrtf(1.0f + (float)deg[i]);
}

// ---------------- gather aggregation (no atomics) ----------------
// agg[n] = h[n]*dinv[n]^2 + sum_{e: dst==n} dinv[src]*dinv[n]*h[src]
__global__ void k_gather96(const int* __restrict__ off, const int* __restrict__ csrc,
                           const float* __restrict__ dinv, const float* __restrict__ h,
                           float* __restrict__ agg) {
  int i = blockIdx.x * 256 + threadIdx.x;
  if (i >= N_TOT * 24) return;
  int n = i / 24;
  int c4 = (i % 24) << 2;
  float di = dinv[n];
  float4 v = *(const float4*)(h + (size_t)n * 96 + c4);
  float w0 = di * di;
  float4 acc = make_float4(v.x * w0, v.y * w0, v.z * w0, v.w * w0);
  int e0 = off[n], e1 = off[n + 1];
  for (int e = e0; e < e1; ++e) {
    int s = csrc[e];
    float w = dinv[s] * di;
    float4 u = *(const float4*)(h + (size_t)s * 96 + c4);
    acc.x += u.x * w; acc.y += u.y * w; acc.z += u.z * w; acc.w += u.w * w;
  }
  *(float4*)(agg + (size_t)n * 96 + c4) = acc;
}

__global__ void k_gather256(const int* __restrict__ off, const int* __restrict__ csrc,
                            const float* __restrict__ dinv, const float* __restrict__ h1,
                            float* __restrict__ agg) {
  int i = blockIdx.x * 256 + threadIdx.x;
  if (i >= N_GRID * 64) return;
  int n = i >> 6;
  int c4 = (i & 63) << 2;
  float di = dinv[n];
  float4 v = *(const float4*)(h1 + (size_t)n * 256 + c4);
  float w0 = di * di;
  float4 acc = make_float4(v.x * w0, v.y * w0, v.z * w0, v.w * w0);
  int e0 = off[n], e1 = off[n + 1];
  for (int e = e0; e < e1; ++e) {
    int s = csrc[e];
    float w = dinv[s] * di;
    float4 u = *(const float4*)(h1 + (size_t)s * 256 + c4);
    acc.x += u.x * w; acc.y += u.y * w; acc.z += u.z * w; acc.w += u.w * w;
  }
  *(float4*)(agg + (size_t)n * 256 + c4) = acc;
}

// ---------------- fp32 tiled GEMM: C(MxN) = A(MxK) @ W(KxN) + bias, opt. gelu, opt. transposed C ----------------
template<int ACT, bool TRANSC>
__global__ __launch_bounds__(256) void k_gemm(const float* __restrict__ A, const float* __restrict__ W,
                                              const float* __restrict__ bias, float* __restrict__ C,
                                              int M, int K, int N, int ldc) {
  constexpr int BM = 128, BN = 128, BK = 32, TM = 8, TN = 8;
  __shared__ float As[BK][BM + 4];
  __shared__ float Ws[BK][BN + 4];
  int t = threadIdx.x;
  int tx = t & 15, ty = t >> 4;
  int bm = blockIdx.y * BM, bn = blockIdx.x * BN;
  float acc[TM][TN] = {};
  for (int bk = 0; bk < K; bk += BK) {
#pragma unroll
    for (int it = 0; it < 4; ++it) {
      int idx = t + it * 256;          // 0..1023 over 128x8(x4)
      int m  = idx >> 3;
      int k4 = (idx & 7) << 2;
      float4 v = make_float4(0.f, 0.f, 0.f, 0.f);
      if (bm + m < M) v = *(const float4*)(A + (size_t)(bm + m) * K + bk + k4);
      As[k4 + 0][m] = v.x;
      As[k4 + 1][m] = v.y;
      As[k4 + 2][m] = v.z;
      As[k4 + 3][m] = v.w;
    }
#pragma unroll
    for (int it = 0; it < 4; ++it) {
      int idx = t + it * 256;
      int k  = idx >> 5;
      int j4 = (idx & 31) << 2;
      float4 v = make_float4(0.f, 0.f, 0.f, 0.f);
      if (bn + j4 < N) v = *(const float4*)(W + (size_t)(bk + k) * N + bn + j4);
      *(float4*)(&Ws[k][j4]) = v;
    }
    __syncthreads();
#pragma unroll
    for (int k = 0; k < BK; ++k) {
      float a[TM], w[TN];
      *(float4*)&a[0] = *(const float4*)(&As[k][ty * TM]);
      *(float4*)&a[4] = *(const float4*)(&As[k][ty * TM + 4]);
      *(float4*)&w[0] = *(const float4*)(&Ws[k][tx * TN]);
      *(float4*)&w[4] = *(const float4*)(&Ws[k][tx * TN + 4]);
#pragma unroll
      for (int im = 0; im < TM; ++im)
#pragma unroll
        for (int jn = 0; jn < TN; ++jn)
          acc[im][jn] += a[im] * w[jn];
    }
    __syncthreads();
  }
#pragma unroll
  for (int im = 0; im < TM; ++im) {
    int gm = bm + ty * TM + im;
    if (gm >= M) continue;
#pragma unroll
    for (int jn = 0; jn < TN; ++jn) {
      int gj = bn + tx * TN + jn;
      if (gj >= N) continue;
      float v = acc[im][jn] + bias[gj];
      if (ACT) v = 0.5f * v * (1.0f + erff(v * 0.70710678118654752f));
      if (TRANSC) C[(size_t)gj * ldc + gm] = v;
      else        C[(size_t)gm * ldc + gj] = v;
    }
  }
}

extern "C" void kernel_launch(void* const* d_in, const int* in_sizes, int n_in,
                              void* d_out, int out_size, void* d_ws, size_t ws_size,
                              hipStream_t stream) {
  const float* xm  = (const float*)d_in[0];   // x: (96, N_MESH)
  const float* xg  = (const float*)d_in[1];   // x_res_grid: (96, N_GRID)
  const int*   ei  = (const int*)d_in[2];     // (2, E)
  const float* W1  = (const float*)d_in[3];
  const float* b1  = (const float*)d_in[4];
  const float* W2  = (const float*)d_in[5];
  const float* b2  = (const float*)d_in[6];
  const float* Wl1 = (const float*)d_in[7];
  const float* bl1 = (const float*)d_in[8];
  const float* Wl2 = (const float*)d_in[9];
  const float* bl2 = (const float*)d_in[10];
  float* out = (float*)d_out;

  // ---- workspace layout (float offsets), liveness-packed; peak ~179 MB ----
  // [0, 16,680,960)           agg1 (t3-t4) / agg2 (t5-t6) / tb (t7-t8)
  // [16,680,960, 17,627,244)  CSR metadata: dinv, deg, off, cur, bsum, csrc (t2-t5)
  //                           g overlays from 16,680,960 (t6-t7, metadata dead)
  // [17,627,244, 44,794,476)  h (t1-t3) then h1 (t4-t5)
  float* W0 = (float*)d_ws;
  const size_t R0 = 0;                              // agg1/agg2/tb
  const size_t RM = (size_t)N_GRID * 256;           // 16,680,960 meta base
  float* dinv = W0 + RM;
  int*   deg  = (int*)(dinv + N_TOT);
  int*   off  = deg + N_TOT;                        // N_TOT+1 entries
  int*   cur  = off + N_TOT + 1;
  int*   bsum = cur + N_TOT;                        // 512 entries
  int*   csrc = bsum + 512;                         // NE entries
  const size_t RH = 17627244;                       // h / h1 base (16B aligned)
  float* h    = W0 + RH;
  float* h1   = W0 + RH;
  float* agg1 = W0 + R0;
  float* agg2 = W0 + R0;
  float* g    = W0 + RM;
  float* tb   = W0 + R0;

  const int* esrc = ei;
  const int* edst = ei + NE;
  dim3 b256(256);
  const int NB_N = (N_TOT + 255) / 256;   // 415

  // t1. node features (N_TOT, 96)
  k_concat_transpose<<<dim3((N_TOT + 63) / 64), b256, 0, stream>>>(xg, xm, h);

  // t2. CSR by dst + dinv
  k_zeroi<<<dim3(NB_N), b256, 0, stream>>>(deg, N_TOT);
  k_hist<<<dim3((NE + 255) / 256), b256, 0, stream>>>(edst, deg);
  k_blocksum<<<dim3(NB_N), b256, 0, stream>>>(deg, bsum, N_TOT);
  k_scanbsum<<<dim3(1), dim3(512), 0, stream>>>(bsum, NB_N);
  k_offsets<<<dim3(NB_N), b256, 0, stream>>>(deg, bsum, off, cur, N_TOT);
  k_seti<<<dim3(1), dim3(1), 0, stream>>>(off + N_TOT, NE);
  k_fillcsr<<<dim3((NE + 255) / 256), b256, 0, stream>>>(esrc, edst, cur, csrc);
  k_dinv<<<dim3(NB_N), b256, 0, stream>>>(deg, dinv, N_TOT);

  // t3. agg1 = S @ h   (96 ch, gather)
  k_gather96<<<dim3((N_TOT * 24 + 255) / 256), b256, 0, stream>>>(off, csrc, dinv, h, agg1);

  // t4. h1 = gelu(agg1 @ W1 + b1)   (N_TOT, 256)
  k_gemm<1, false><<<dim3(2, (N_TOT + 127) / 128), b256, 0, stream>>>(agg1, W1, b1, h1, N_TOT, 96, 256, 256);

  // t5. agg2 = S @ h1 for dst < N_GRID   (256 ch, gather)
  k_gather256<<<dim3((N_GRID * 64 + 255) / 256), b256, 0, stream>>>(off, csrc, dinv, h1, agg2);

  // t6. g = agg2 @ W2 + b2   (N_GRID, 256)
  k_gemm<0, false><<<dim3(2, (N_GRID + 127) / 128), b256, 0, stream>>>(agg2, W2, b2, g, N_GRID, 256, 256, 256);

  // t7. tb = g @ Wl1 + bl1
  k_gemm<0, false><<<dim3(2, (N_GRID + 127) / 128), b256, 0, stream>>>(g, Wl1, bl1, tb, N_GRID, 256, 256, 256);

  // t8. out^T = (tb @ Wl2 + bl2)^T  -> (96, N_GRID)
  k_gemm<0, true><<<dim3(1, (N_GRID + 127) / 128), b256, 0, stream>>>(tb, Wl2, bl2, out, N_GRID, 256, 96, N_GRID);
}